// Round 5
// baseline (3016.887 us; speedup 1.0000x reference)
//
#include <hip/hip_runtime.h>
#include <hip/hip_cooperative_groups.h>

typedef short bfv8 __attribute__((ext_vector_type(8)));  // 8 x bf16 (4 VGPRs)
typedef float fv4  __attribute__((ext_vector_type(4)));  // 4 x f32 accum
typedef unsigned long long u64;

#define T_STEPS 128
#define BATCH   64
#define FDIM    512
#define HDIM    1024
#define NCOL    4096   // 4*HDIM, gate-interleaved: n = j*4 + g (g: 0=f,1=i,2=o,3=c)
#define NCLS    513
#define NBLK    256
#define HSLOT   65536  // elements per h ring slot (64 x 1024)

static __device__ __forceinline__ float b2f(unsigned short u) {
  union { unsigned int i; float f; } v; v.i = ((unsigned int)u) << 16; return v.f;
}
static __device__ __forceinline__ unsigned short f2b(float f) {
  union { float f; unsigned int i; } v; v.f = f;
  unsigned int r = v.i + 0x7FFFu + ((v.i >> 16) & 1u);   // RNE
  return (unsigned short)(r >> 16);
}
static __device__ __forceinline__ float sigm(float x) { return 1.0f / (1.0f + __expf(-x)); }
static __device__ __forceinline__ float tanh_f(float x) {
  float e = __expf(-2.0f * fabsf(x));
  float t = (1.0f - e) / (1.0f + e);
  return x >= 0.0f ? t : -t;
}

// ---- dtype detector: bf16 mode iff even-index ushorts look like bf16 N(0,1) ----
__global__ void detect_k(const unsigned short* __restrict__ xr, int* __restrict__ flag) {
  __shared__ int cnt;
  if (threadIdx.x == 0) cnt = 0;
  __syncthreads();
  int local = 0;
  for (int s = 0; s < 4; ++s) {
    int i = threadIdx.x + 256 * s;
    unsigned short u = xr[2 * i];
    int e = (u >> 7) & 0xFF;
    if (e >= 112 && e <= 131) local++;
  }
  atomicAdd(&cnt, local);
  __syncthreads();
  if (threadIdx.x == 0) *flag = (cnt >= 512) ? 1 : 0;
}

// ---- x -> bf16 (copy or convert) ----
__global__ void convert_x_k(const void* __restrict__ x, const int* __restrict__ flagp,
                            unsigned short* __restrict__ xbf) {
  int idx = blockIdx.x * 256 + threadIdx.x;
  if (*flagp) xbf[idx] = ((const unsigned short*)x)[idx];
  else        xbf[idx] = f2b(((const float*)x)[idx]);
}

// Tessarine block table: comp = rb ^ cb ; sign = - iff (rb odd) && (cb even).
__global__ void expand_x_k(const void* w0, const void* w1, const void* w2, const void* w3,
                           const int* __restrict__ flagp, unsigned short* __restrict__ WXT) {
  int idx = blockIdx.x * 256 + threadIdx.x;
  int n = idx >> 9, k = idx & 511;
  int j = n >> 2, g = n & 3;
  int rb = k >> 7, p = k & 127;
  int cb = j >> 8, q = j & 255;
  int comp = rb ^ cb;
  int neg = (rb & 1) && !(cb & 1);
  const void* W = (g == 0) ? w0 : (g == 1) ? w1 : (g == 2) ? w2 : w3;
  int off = comp * (128 * 256) + p * 256 + q;
  unsigned short v;
  if (*flagp) { v = ((const unsigned short*)W)[off]; if (neg) v ^= 0x8000u; }
  else        { float f = ((const float*)W)[off]; if (neg) f = -f; v = f2b(f); }
  WXT[idx] = v;
}

__global__ void expand_h_k(const void* w0, const void* w1, const void* w2, const void* w3,
                           const int* __restrict__ flagp, unsigned short* __restrict__ WHT) {
  int idx = blockIdx.x * 256 + threadIdx.x;
  int n = idx >> 10, k = idx & 1023;
  int j = n >> 2, g = n & 3;
  int rb = k >> 8, p = k & 255;
  int cb = j >> 8, q = j & 255;
  int comp = rb ^ cb;
  int neg = (rb & 1) && !(cb & 1);
  const void* W = (g == 0) ? w0 : (g == 1) ? w1 : (g == 2) ? w2 : w3;
  int off = comp * (256 * 256) + p * 256 + q;
  unsigned short v;
  if (*flagp) { v = ((const unsigned short*)W)[off]; if (neg) v ^= 0x8000u; }
  else        { float f = ((const float*)W)[off]; if (neg) f = -f; v = f2b(f); }
  WHT[idx] = v;
}

__global__ void bias_k(const void* b0, const void* b1, const void* b2, const void* b3,
                       const int* __restrict__ flagp, float* __restrict__ biasI) {
  int idx = blockIdx.x * 256 + threadIdx.x;
  int j = idx >> 2, g = idx & 3;
  const void* B = (g == 0) ? b0 : (g == 1) ? b1 : (g == 2) ? b2 : b3;
  biasI[idx] = (*flagp) ? b2f(((const unsigned short*)B)[j]) : ((const float*)B)[j];
}

// ---- Phase B: 128-step recurrence. Ring-buffered h + custom IF$-level barrier.
// __launch_bounds__(256, 1): cooperative 1 block/CU -> 1 wave/EU -> 512-VGPR
// budget; lets the compiler keep the 32x uint4 h-staging array (128 VGPRs) in
// registers instead of spilling 512 B/thread to scratch (the round-4 33 MB/step
// WRITE_SIZE). ----
__global__ void __launch_bounds__(256, 1) phaseB_k(const unsigned short* __restrict__ xbf,
                                                   const unsigned short* __restrict__ WXT,
                                                   const unsigned short* __restrict__ WHT,
                                                   const float* __restrict__ biasI,
                                                   unsigned short* __restrict__ hring,
                                                   int* __restrict__ cnt) {
  __shared__ unsigned short Wh[16][1032];     // 16 n-cols x 1024 k (+8 pad)
  __shared__ unsigned short Wx[16][520];      // 16 n-cols x  512 k (+8 pad)
  __shared__ float Pl[4][16][16];             // per-wave 16x16 f32 staging
  int tid = threadIdx.x;
  int n0 = blockIdx.x * 16;
  int j0 = blockIdx.x * 4;
  for (int c = tid; c < 16 * 128; c += 256) {
    int row = c >> 7, ch = c & 127;
    *(uint4*)&Wh[row][ch * 8] = *(const uint4*)&WHT[(n0 + row) * HDIM + ch * 8];
  }
  for (int c = tid; c < 16 * 64; c += 256) {
    int row = c >> 6, ch = c & 63;
    *(uint4*)&Wx[row][ch * 8] = *(const uint4*)&WXT[(n0 + row) * FDIM + ch * 8];
  }
  __syncthreads();
  int w = tid >> 6, lane = tid & 63;
  int col = lane & 15, quad = lane >> 4;
  int brow = w * 16 + col;                    // batch row (A-operand m AND elementwise b)
  int jl = quad;                              // hidden sub-unit for elementwise
  const unsigned short* whp = &Wh[col][quad * 8];
  const unsigned short* wxp = &Wx[col][quad * 8];
  float4 bv = *(const float4*)&biasI[n0 + jl * 4];
  float creg = 0.0f;                          // c state is thread-private
  for (int t = 0; t < T_STEPS; ++t) {
    const unsigned short* hin  = hring + (size_t)t * HSLOT;
    unsigned short*       hout = hring + (size_t)(t + 1) * HSLOT;
    // Stage this lane's 32 h-fragments in REGISTERS (512-VGPR budget, no spill).
    const uint4* hq = (const uint4*)(hin + brow * HDIM + quad * 8);
    uint4 hs[32];
#pragma unroll
    for (int f = 0; f < 32; ++f) hs[f] = hq[f * 4];   // stride 64 B between fragments
    fv4 acc0 = {0.f, 0.f, 0.f, 0.f};
    fv4 acc1 = {0.f, 0.f, 0.f, 0.f};
    // x-GEMM (L2-cached loads) while h fills are in flight.
    const unsigned short* xrow = xbf + (t * BATCH + brow) * FDIM + quad * 8;
#pragma unroll 4
    for (int k0 = 0; k0 < FDIM; k0 += 64) {
      bfv8 a0 = *(const bfv8*)(xrow + k0);
      bfv8 b0 = *(const bfv8*)(wxp + k0);
      bfv8 a1 = *(const bfv8*)(xrow + k0 + 32);
      bfv8 b1 = *(const bfv8*)(wxp + k0 + 32);
      acc0 = __builtin_amdgcn_mfma_f32_16x16x32_bf16(a0, b0, acc0, 0, 0, 0);
      acc1 = __builtin_amdgcn_mfma_f32_16x16x32_bf16(a1, b1, acc1, 0, 0, 0);
    }
    // h-GEMM from staged registers + LDS weights.
#pragma unroll 4
    for (int f = 0; f < 32; f += 2) {
      union { uint4 q; bfv8 v; } ua, ub;
      ua.q = hs[f];
      ub.q = hs[f + 1];
      bfv8 b0 = *(const bfv8*)(whp + f * 32);
      bfv8 b1 = *(const bfv8*)(whp + f * 32 + 32);
      acc0 = __builtin_amdgcn_mfma_f32_16x16x32_bf16(ua.v, b0, acc0, 0, 0, 0);
      acc1 = __builtin_amdgcn_mfma_f32_16x16x32_bf16(ub.v, b1, acc1, 0, 0, 0);
    }
    fv4 acc = acc0 + acc1;
#pragma unroll
    for (int r = 0; r < 4; ++r) Pl[w][quad * 4 + r][col] = acc[r];  // D: row=quad*4+r, col=lane&15
    __syncthreads();
    float4 pv = *(const float4*)&Pl[w][col][jl * 4];  // (b_local=col, 4 gates of unit j0+jl)
    float fg = sigm(pv.x + bv.x);
    float ig = sigm(pv.y + bv.y);
    float og = sigm(pv.z + bv.z);
    float av = pv.w + bv.w;
    float cn = ig * tanh_f(av) + fg * creg;
    float hn = og * tanh_f(cn);
    creg = cn;
    // Pack 4 consecutive j (quad 0..3) via shuffles -> one 8B write-through store.
    unsigned int u = f2b(hn);
    unsigned int a0 = __shfl((int)u, col, 64);
    unsigned int a1 = __shfl((int)u, col + 16, 64);
    unsigned int a2 = __shfl((int)u, col + 32, 64);
    unsigned int a3 = __shfl((int)u, col + 48, 64);
    if (quad == 0) {
      u64 pk = (u64)(a0 & 0xFFFFu) | ((u64)(a1 & 0xFFFFu) << 16)
             | ((u64)(a2 & 0xFFFFu) << 32) | ((u64)(a3 & 0xFFFFu) << 48);
      __hip_atomic_store((u64*)(hout + brow * HDIM + j0), pk,
                         __ATOMIC_RELAXED, __HIP_MEMORY_SCOPE_AGENT);
    }
    asm volatile("" ::: "memory");
    __builtin_amdgcn_s_waitcnt(0);            // drain write-through stores to IF$
    __syncthreads();                          // all waves in block drained
    if (tid == 0) {
      __hip_atomic_fetch_add(&cnt[t * 16], 1, __ATOMIC_RELAXED, __HIP_MEMORY_SCOPE_AGENT);
      while (__hip_atomic_load(&cnt[t * 16], __ATOMIC_RELAXED, __HIP_MEMORY_SCOPE_AGENT) < NBLK)
        __builtin_amdgcn_s_sleep(2);
    }
    __syncthreads();
    asm volatile("" ::: "memory");            // no load hoisting above the barrier
  }
}

// ---- Phase C: out = h @ fco_W + fco_b ----
__global__ void phaseC_k(const unsigned short* __restrict__ h,
                         const void* __restrict__ fw, const void* __restrict__ fb,
                         const int* __restrict__ flagp, void* __restrict__ out) {
  int idx = blockIdx.x * 256 + threadIdx.x;
  if (idx >= BATCH * NCLS) return;
  int b = idx / NCLS, cc = idx - b * NCLS;
  const unsigned short* hr = h + b * HDIM;
  float acc = 0.f;
  if (*flagp) {
    const unsigned short* fwp = (const unsigned short*)fw;
    for (int k = 0; k < HDIM; ++k)
      acc = fmaf(b2f(hr[k]), b2f(fwp[k * NCLS + cc]), acc);
    acc += b2f(((const unsigned short*)fb)[cc]);
    ((unsigned short*)out)[idx] = f2b(acc);
  } else {
    const float* fwp = (const float*)fw;
    for (int k = 0; k < HDIM; ++k)
      acc = fmaf(b2f(hr[k]), fwp[k * NCLS + cc], acc);
    acc += ((const float*)fb)[cc];
    ((float*)out)[idx] = acc;
  }
}

extern "C" void kernel_launch(void* const* d_in, const int* in_sizes, int n_in,
                              void* d_out, int out_size, void* d_ws, size_t ws_size,
                              hipStream_t stream) {
  const void* x   = d_in[0];
  const void* wfx = d_in[1];  const void* bfv = d_in[2];  const void* wfh = d_in[3];
  const void* wix = d_in[4];  const void* biv = d_in[5];  const void* wih = d_in[6];
  const void* wox = d_in[7];  const void* bov = d_in[8];  const void* woh = d_in[9];
  const void* wcx = d_in[10]; const void* bcv = d_in[11]; const void* wch = d_in[12];
  const void* fcw = d_in[13]; const void* fcb = d_in[14];

  char* ws = (char*)d_ws;
  int*            flag  = (int*)           (ws);                 // 256 B
  unsigned short* WXT   = (unsigned short*)(ws + 256);           // 4 MB
  unsigned short* WHT   = (unsigned short*)(ws + 4194560);       // 8 MB
  float*          biasI = (float*)         (ws + 12583168);      // 16 KB
  unsigned short* xbf   = (unsigned short*)(ws + 12599552);      // 8 MB
  unsigned short* hring = (unsigned short*)(ws + 20988160);      // 129 x 128 KB = 16.9 MB
  int*            cnt   = (int*)           (ws + 37896448);      // 8 KB -> total ~37.9 MB

  detect_k<<<1, 256, 0, stream>>>((const unsigned short*)x, flag);
  convert_x_k<<<(T_STEPS * BATCH * FDIM) / 256, 256, 0, stream>>>(x, flag, xbf);
  expand_x_k<<<(NCOL * FDIM) / 256, 256, 0, stream>>>(wfx, wix, wox, wcx, flag, WXT);
  expand_h_k<<<(NCOL * HDIM) / 256, 256, 0, stream>>>(wfh, wih, woh, wch, flag, WHT);
  bias_k<<<NCOL / 256, 256, 0, stream>>>(bfv, biv, bov, bcv, flag, biasI);
  hipMemsetAsync(hring, 0, 131072, stream);                      // h[0] = 0
  hipMemsetAsync(cnt, 0, 8192, stream);                          // barrier counters

  const unsigned short* p_x = xbf;
  const unsigned short* p_wx = WXT;
  const unsigned short* p_wh = WHT;
  const float* p_bi = biasI;
  unsigned short* p_hr = hring;
  int* p_cn = cnt;
  void* kargs[] = { (void*)&p_x, (void*)&p_wx, (void*)&p_wh, (void*)&p_bi,
                    (void*)&p_hr, (void*)&p_cn };
  hipLaunchCooperativeKernel((void*)phaseB_k, dim3(NBLK), dim3(256), kargs, 0, stream);

  // final h is ring slot 128
  phaseC_k<<<(BATCH * NCLS + 255) / 256, 256, 0, stream>>>(hring + 128 * HSLOT, fcw, fcb,
                                                           flag, d_out);
}

// Round 6
// 1556.827 us; speedup vs baseline: 1.9378x; 1.9378x over previous
//
#include <hip/hip_runtime.h>
#include <hip/hip_cooperative_groups.h>

typedef short bfv8 __attribute__((ext_vector_type(8)));  // 8 x bf16 (4 VGPRs)
typedef float fv4  __attribute__((ext_vector_type(4)));  // 4 x f32 accum
typedef unsigned long long u64;

#define T_STEPS 128
#define BATCH   64
#define FDIM    512
#define HDIM    1024
#define NCOL    4096   // 4*HDIM, gate-interleaved: n = j*4 + g (g: 0=f,1=i,2=o,3=c)
#define NCLS    513
#define NBLK    256
#define HSLOT   65536  // elements per h ring slot (64 x 1024)

static __device__ __forceinline__ float b2f(unsigned short u) {
  union { unsigned int i; float f; } v; v.i = ((unsigned int)u) << 16; return v.f;
}
static __device__ __forceinline__ unsigned short f2b(float f) {
  union { float f; unsigned int i; } v; v.f = f;
  unsigned int r = v.i + 0x7FFFu + ((v.i >> 16) & 1u);   // RNE
  return (unsigned short)(r >> 16);
}
static __device__ __forceinline__ float sigm(float x) { return 1.0f / (1.0f + __expf(-x)); }
static __device__ __forceinline__ float tanh_f(float x) {
  float e = __expf(-2.0f * fabsf(x));
  float t = (1.0f - e) / (1.0f + e);
  return x >= 0.0f ? t : -t;
}

// ---- dtype detector: bf16 mode iff even-index ushorts look like bf16 N(0,1) ----
__global__ void detect_k(const unsigned short* __restrict__ xr, int* __restrict__ flag) {
  __shared__ int cnt;
  if (threadIdx.x == 0) cnt = 0;
  __syncthreads();
  int local = 0;
  for (int s = 0; s < 4; ++s) {
    int i = threadIdx.x + 256 * s;
    unsigned short u = xr[2 * i];
    int e = (u >> 7) & 0xFF;
    if (e >= 112 && e <= 131) local++;
  }
  atomicAdd(&cnt, local);
  __syncthreads();
  if (threadIdx.x == 0) *flag = (cnt >= 512) ? 1 : 0;
}

// ---- x -> bf16 (copy or convert) ----
__global__ void convert_x_k(const void* __restrict__ x, const int* __restrict__ flagp,
                            unsigned short* __restrict__ xbf) {
  int idx = blockIdx.x * 256 + threadIdx.x;
  if (*flagp) xbf[idx] = ((const unsigned short*)x)[idx];
  else        xbf[idx] = f2b(((const float*)x)[idx]);
}

// Tessarine block table: comp = rb ^ cb ; sign = - iff (rb odd) && (cb even).
__global__ void expand_x_k(const void* w0, const void* w1, const void* w2, const void* w3,
                           const int* __restrict__ flagp, unsigned short* __restrict__ WXT) {
  int idx = blockIdx.x * 256 + threadIdx.x;
  int n = idx >> 9, k = idx & 511;
  int j = n >> 2, g = n & 3;
  int rb = k >> 7, p = k & 127;
  int cb = j >> 8, q = j & 255;
  int comp = rb ^ cb;
  int neg = (rb & 1) && !(cb & 1);
  const void* W = (g == 0) ? w0 : (g == 1) ? w1 : (g == 2) ? w2 : w3;
  int off = comp * (128 * 256) + p * 256 + q;
  unsigned short v;
  if (*flagp) { v = ((const unsigned short*)W)[off]; if (neg) v ^= 0x8000u; }
  else        { float f = ((const float*)W)[off]; if (neg) f = -f; v = f2b(f); }
  WXT[idx] = v;
}

__global__ void expand_h_k(const void* w0, const void* w1, const void* w2, const void* w3,
                           const int* __restrict__ flagp, unsigned short* __restrict__ WHT) {
  int idx = blockIdx.x * 256 + threadIdx.x;
  int n = idx >> 10, k = idx & 1023;
  int j = n >> 2, g = n & 3;
  int rb = k >> 8, p = k & 255;
  int cb = j >> 8, q = j & 255;
  int comp = rb ^ cb;
  int neg = (rb & 1) && !(cb & 1);
  const void* W = (g == 0) ? w0 : (g == 1) ? w1 : (g == 2) ? w2 : w3;
  int off = comp * (256 * 256) + p * 256 + q;
  unsigned short v;
  if (*flagp) { v = ((const unsigned short*)W)[off]; if (neg) v ^= 0x8000u; }
  else        { float f = ((const float*)W)[off]; if (neg) f = -f; v = f2b(f); }
  WHT[idx] = v;
}

__global__ void bias_k(const void* b0, const void* b1, const void* b2, const void* b3,
                       const int* __restrict__ flagp, float* __restrict__ biasI) {
  int idx = blockIdx.x * 256 + threadIdx.x;
  int j = idx >> 2, g = idx & 3;
  const void* B = (g == 0) ? b0 : (g == 1) ? b1 : (g == 2) ? b2 : b3;
  biasI[idx] = (*flagp) ? b2f(((const unsigned short*)B)[j]) : ((const float*)B)[j];
}

// ---- Phase B: 128-step recurrence. Ring-buffered h + custom IF$-level barrier.
// ALL loops touching hs[] are FULLY unrolled: constant indices -> SROA keeps the
// 32x uint4 staging array in 128 VGPRs (rounds 3-5 spilled it to write-through
// scratch = 32 MiB/step HBM writes). __launch_bounds__(256,1) gives the 512-VGPR
// budget (cooperative 1 block/CU -> 1 wave/EU). ----
__global__ void __launch_bounds__(256, 1) phaseB_k(const unsigned short* __restrict__ xbf,
                                                   const unsigned short* __restrict__ WXT,
                                                   const unsigned short* __restrict__ WHT,
                                                   const float* __restrict__ biasI,
                                                   unsigned short* __restrict__ hring,
                                                   int* __restrict__ cnt) {
  __shared__ unsigned short Wh[16][1032];     // 16 n-cols x 1024 k (+8 pad)
  __shared__ unsigned short Wx[16][520];      // 16 n-cols x  512 k (+8 pad)
  __shared__ float Pl[4][16][16];             // per-wave 16x16 f32 staging
  int tid = threadIdx.x;
  int n0 = blockIdx.x * 16;
  int j0 = blockIdx.x * 4;
  for (int c = tid; c < 16 * 128; c += 256) {
    int row = c >> 7, ch = c & 127;
    *(uint4*)&Wh[row][ch * 8] = *(const uint4*)&WHT[(n0 + row) * HDIM + ch * 8];
  }
  for (int c = tid; c < 16 * 64; c += 256) {
    int row = c >> 6, ch = c & 63;
    *(uint4*)&Wx[row][ch * 8] = *(const uint4*)&WXT[(n0 + row) * FDIM + ch * 8];
  }
  __syncthreads();
  int w = tid >> 6, lane = tid & 63;
  int col = lane & 15, quad = lane >> 4;
  int brow = w * 16 + col;                    // batch row (A-operand m AND elementwise b)
  int jl = quad;                              // hidden sub-unit for elementwise
  const unsigned short* whp = &Wh[col][quad * 8];
  const unsigned short* wxp = &Wx[col][quad * 8];
  float4 bv = *(const float4*)&biasI[n0 + jl * 4];
  float creg = 0.0f;                          // c state is thread-private
  for (int t = 0; t < T_STEPS; ++t) {
    const unsigned short* hin  = hring + (size_t)t * HSLOT;
    unsigned short*       hout = hring + (size_t)(t + 1) * HSLOT;
    // Stage this lane's 32 h-fragments in REGISTERS. FULL unroll -> constant
    // indices -> SROA promotion (no scratch).
    const uint4* hq = (const uint4*)(hin + brow * HDIM + quad * 8);
    uint4 hs[32];
#pragma unroll
    for (int f = 0; f < 32; ++f) hs[f] = hq[f * 4];   // stride 64 B between fragments
    fv4 acc0 = {0.f, 0.f, 0.f, 0.f};
    fv4 acc1 = {0.f, 0.f, 0.f, 0.f};
    // x-GEMM (L2-cached loads) while h fills are in flight.
    const unsigned short* xrow = xbf + (t * BATCH + brow) * FDIM + quad * 8;
#pragma unroll
    for (int k0 = 0; k0 < FDIM; k0 += 64) {
      bfv8 a0 = *(const bfv8*)(xrow + k0);
      bfv8 b0 = *(const bfv8*)(wxp + k0);
      bfv8 a1 = *(const bfv8*)(xrow + k0 + 32);
      bfv8 b1 = *(const bfv8*)(wxp + k0 + 32);
      acc0 = __builtin_amdgcn_mfma_f32_16x16x32_bf16(a0, b0, acc0, 0, 0, 0);
      acc1 = __builtin_amdgcn_mfma_f32_16x16x32_bf16(a1, b1, acc1, 0, 0, 0);
    }
    // h-GEMM from staged registers + LDS weights. FULL unroll (constant hs idx).
#pragma unroll
    for (int f = 0; f < 32; f += 2) {
      union { uint4 q; bfv8 v; } ua, ub;
      ua.q = hs[f];
      ub.q = hs[f + 1];
      bfv8 b0 = *(const bfv8*)(whp + f * 32);
      bfv8 b1 = *(const bfv8*)(whp + f * 32 + 32);
      acc0 = __builtin_amdgcn_mfma_f32_16x16x32_bf16(ua.v, b0, acc0, 0, 0, 0);
      acc1 = __builtin_amdgcn_mfma_f32_16x16x32_bf16(ub.v, b1, acc1, 0, 0, 0);
    }
    fv4 acc = acc0 + acc1;
#pragma unroll
    for (int r = 0; r < 4; ++r) Pl[w][quad * 4 + r][col] = acc[r];  // D: row=quad*4+r, col=lane&15
    __syncthreads();
    float4 pv = *(const float4*)&Pl[w][col][jl * 4];  // (b_local=col, 4 gates of unit j0+jl)
    float fg = sigm(pv.x + bv.x);
    float ig = sigm(pv.y + bv.y);
    float og = sigm(pv.z + bv.z);
    float av = pv.w + bv.w;
    float cn = ig * tanh_f(av) + fg * creg;
    float hn = og * tanh_f(cn);
    creg = cn;
    // Pack 4 consecutive j (quad 0..3) via shuffles -> one 8B write-through store.
    unsigned int u = f2b(hn);
    unsigned int a0 = __shfl((int)u, col, 64);
    unsigned int a1 = __shfl((int)u, col + 16, 64);
    unsigned int a2 = __shfl((int)u, col + 32, 64);
    unsigned int a3 = __shfl((int)u, col + 48, 64);
    if (quad == 0) {
      u64 pk = (u64)(a0 & 0xFFFFu) | ((u64)(a1 & 0xFFFFu) << 16)
             | ((u64)(a2 & 0xFFFFu) << 32) | ((u64)(a3 & 0xFFFFu) << 48);
      __hip_atomic_store((u64*)(hout + brow * HDIM + j0), pk,
                         __ATOMIC_RELAXED, __HIP_MEMORY_SCOPE_AGENT);
    }
    asm volatile("" ::: "memory");
    __builtin_amdgcn_s_waitcnt(0);            // drain write-through stores to IF$
    __syncthreads();                          // all waves in block drained
    if (tid == 0) {
      __hip_atomic_fetch_add(&cnt[t * 16], 1, __ATOMIC_RELAXED, __HIP_MEMORY_SCOPE_AGENT);
      while (__hip_atomic_load(&cnt[t * 16], __ATOMIC_RELAXED, __HIP_MEMORY_SCOPE_AGENT) < NBLK)
        __builtin_amdgcn_s_sleep(2);
    }
    __syncthreads();
    asm volatile("" ::: "memory");            // no load hoisting above the barrier
  }
}

// ---- Phase C: out = h @ fco_W + fco_b ----
__global__ void phaseC_k(const unsigned short* __restrict__ h,
                         const void* __restrict__ fw, const void* __restrict__ fb,
                         const int* __restrict__ flagp, void* __restrict__ out) {
  int idx = blockIdx.x * 256 + threadIdx.x;
  if (idx >= BATCH * NCLS) return;
  int b = idx / NCLS, cc = idx - b * NCLS;
  const unsigned short* hr = h + b * HDIM;
  float acc = 0.f;
  if (*flagp) {
    const unsigned short* fwp = (const unsigned short*)fw;
    for (int k = 0; k < HDIM; ++k)
      acc = fmaf(b2f(hr[k]), b2f(fwp[k * NCLS + cc]), acc);
    acc += b2f(((const unsigned short*)fb)[cc]);
    ((unsigned short*)out)[idx] = f2b(acc);
  } else {
    const float* fwp = (const float*)fw;
    for (int k = 0; k < HDIM; ++k)
      acc = fmaf(b2f(hr[k]), fwp[k * NCLS + cc], acc);
    acc += ((const float*)fb)[cc];
    ((float*)out)[idx] = acc;
  }
}

extern "C" void kernel_launch(void* const* d_in, const int* in_sizes, int n_in,
                              void* d_out, int out_size, void* d_ws, size_t ws_size,
                              hipStream_t stream) {
  const void* x   = d_in[0];
  const void* wfx = d_in[1];  const void* bfv = d_in[2];  const void* wfh = d_in[3];
  const void* wix = d_in[4];  const void* biv = d_in[5];  const void* wih = d_in[6];
  const void* wox = d_in[7];  const void* bov = d_in[8];  const void* woh = d_in[9];
  const void* wcx = d_in[10]; const void* bcv = d_in[11]; const void* wch = d_in[12];
  const void* fcw = d_in[13]; const void* fcb = d_in[14];

  char* ws = (char*)d_ws;
  int*            flag  = (int*)           (ws);                 // 256 B
  unsigned short* WXT   = (unsigned short*)(ws + 256);           // 4 MB
  unsigned short* WHT   = (unsigned short*)(ws + 4194560);       // 8 MB
  float*          biasI = (float*)         (ws + 12583168);      // 16 KB
  unsigned short* xbf   = (unsigned short*)(ws + 12599552);      // 8 MB
  unsigned short* hring = (unsigned short*)(ws + 20988160);      // 129 x 128 KB = 16.9 MB
  int*            cnt   = (int*)           (ws + 37896448);      // 8 KB -> total ~37.9 MB

  detect_k<<<1, 256, 0, stream>>>((const unsigned short*)x, flag);
  convert_x_k<<<(T_STEPS * BATCH * FDIM) / 256, 256, 0, stream>>>(x, flag, xbf);
  expand_x_k<<<(NCOL * FDIM) / 256, 256, 0, stream>>>(wfx, wix, wox, wcx, flag, WXT);
  expand_h_k<<<(NCOL * HDIM) / 256, 256, 0, stream>>>(wfh, wih, woh, wch, flag, WHT);
  bias_k<<<NCOL / 256, 256, 0, stream>>>(bfv, biv, bov, bcv, flag, biasI);
  hipMemsetAsync(hring, 0, 131072, stream);                      // h[0] = 0
  hipMemsetAsync(cnt, 0, 8192, stream);                          // barrier counters

  const unsigned short* p_x = xbf;
  const unsigned short* p_wx = WXT;
  const unsigned short* p_wh = WHT;
  const float* p_bi = biasI;
  unsigned short* p_hr = hring;
  int* p_cn = cnt;
  void* kargs[] = { (void*)&p_x, (void*)&p_wx, (void*)&p_wh, (void*)&p_bi,
                    (void*)&p_hr, (void*)&p_cn };
  hipLaunchCooperativeKernel((void*)phaseB_k, dim3(NBLK), dim3(256), kargs, 0, stream);

  // final h is ring slot 128
  phaseC_k<<<(BATCH * NCLS + 255) / 256, 256, 0, stream>>>(hring + 128 * HSLOT, fcw, fcb,
                                                           flag, d_out);
}

// Round 7
// 1399.288 us; speedup vs baseline: 2.1560x; 1.1126x over previous
//
#include <hip/hip_runtime.h>
#include <hip/hip_cooperative_groups.h>

typedef short bfv8 __attribute__((ext_vector_type(8)));  // 8 x bf16 (4 VGPRs)
typedef float fv4  __attribute__((ext_vector_type(4)));  // 4 x f32 accum
typedef unsigned long long u64;

#define T_STEPS 128
#define BATCH   64
#define FDIM    512
#define HDIM    1024
#define NCOL    4096   // 4*HDIM, gate-interleaved: n = j*4 + g (g: 0=f,1=i,2=o,3=c)
#define NCLS    513
#define HSLOT   65536  // elements per h ring slot (64 x 1024)

#define PREP_N0 4194304            // convert_x  (T*B*F)
#define PREP_N1 2097152            // expand_x   (NCOL*FDIM)
#define PREP_N2 4194304            // expand_h   (NCOL*HDIM)
#define PREP_N3 4096               // bias
#define PREP_TOTAL (PREP_N0 + PREP_N1 + PREP_N2 + PREP_N3)

static __device__ __forceinline__ float b2f(unsigned short u) {
  union { unsigned int i; float f; } v; v.i = ((unsigned int)u) << 16; return v.f;
}
static __device__ __forceinline__ unsigned short f2b(float f) {
  union { float f; unsigned int i; } v; v.f = f;
  unsigned int r = v.i + 0x7FFFu + ((v.i >> 16) & 1u);   // RNE
  return (unsigned short)(r >> 16);
}
static __device__ __forceinline__ float sigm(float x) { return 1.0f / (1.0f + __expf(-x)); }
static __device__ __forceinline__ float tanh_f(float x) {
  float e = __expf(-2.0f * fabsf(x));
  float t = (1.0f - e) / (1.0f + e);
  return x >= 0.0f ? t : -t;
}

// ---- dtype detector: bf16 mode iff even-index ushorts look like bf16 N(0,1) ----
__global__ void detect_k(const unsigned short* __restrict__ xr, int* __restrict__ flag) {
  __shared__ int cnt;
  if (threadIdx.x == 0) cnt = 0;
  __syncthreads();
  int local = 0;
  for (int s = 0; s < 4; ++s) {
    int i = threadIdx.x + 256 * s;
    unsigned short u = xr[2 * i];
    int e = (u >> 7) & 0xFF;
    if (e >= 112 && e <= 131) local++;
  }
  atomicAdd(&cnt, local);
  __syncthreads();
  if (threadIdx.x == 0) *flag = (cnt >= 512) ? 1 : 0;
}

// ---- merged prep: convert x, expand WXT/WHT (tessarine big, transposed,
// gate-interleaved), bias. comp = rb ^ cb ; sign = - iff (rb odd) && (cb even).
__global__ void prep_k(const void* __restrict__ x,
                       const void* w0x, const void* w1x, const void* w2x, const void* w3x,
                       const void* w0h, const void* w1h, const void* w2h, const void* w3h,
                       const void* b0, const void* b1, const void* b2, const void* b3,
                       const int* __restrict__ flagp,
                       unsigned short* __restrict__ xbf,
                       unsigned short* __restrict__ WXT,
                       unsigned short* __restrict__ WHT,
                       float* __restrict__ biasI) {
  int fl = *flagp;
  long idx = (long)blockIdx.x * 256 + threadIdx.x;
  if (idx < PREP_N0) {
    int i = (int)idx;
    xbf[i] = fl ? ((const unsigned short*)x)[i] : f2b(((const float*)x)[i]);
    return;
  }
  idx -= PREP_N0;
  if (idx < PREP_N1) {
    int i = (int)idx;
    int n = i >> 9, k = i & 511;
    int j = n >> 2, g = n & 3;
    int rb = k >> 7, p = k & 127;               // FDIM/4 = 128
    int cb = j >> 8, q = j & 255;               // HDIM/4 = 256
    int comp = rb ^ cb;
    int neg = (rb & 1) && !(cb & 1);
    const void* W = (g == 0) ? w0x : (g == 1) ? w1x : (g == 2) ? w2x : w3x;
    int off = comp * (128 * 256) + p * 256 + q;
    unsigned short v;
    if (fl) { v = ((const unsigned short*)W)[off]; if (neg) v ^= 0x8000u; }
    else    { float f = ((const float*)W)[off]; if (neg) f = -f; v = f2b(f); }
    WXT[i] = v;
    return;
  }
  idx -= PREP_N1;
  if (idx < PREP_N2) {
    int i = (int)idx;
    int n = i >> 10, k = i & 1023;
    int j = n >> 2, g = n & 3;
    int rb = k >> 8, p = k & 255;               // HDIM/4 = 256
    int cb = j >> 8, q = j & 255;
    int comp = rb ^ cb;
    int neg = (rb & 1) && !(cb & 1);
    const void* W = (g == 0) ? w0h : (g == 1) ? w1h : (g == 2) ? w2h : w3h;
    int off = comp * (256 * 256) + p * 256 + q;
    unsigned short v;
    if (fl) { v = ((const unsigned short*)W)[off]; if (neg) v ^= 0x8000u; }
    else    { float f = ((const float*)W)[off]; if (neg) f = -f; v = f2b(f); }
    WHT[i] = v;
    return;
  }
  idx -= PREP_N2;
  {
    int i = (int)idx;                           // < 4096
    int j = i >> 2, g = i & 3;
    const void* B = (g == 0) ? b0 : (g == 1) ? b1 : (g == 2) ? b2 : b3;
    biasI[i] = fl ? b2f(((const unsigned short*)B)[j]) : ((const float*)B)[j];
  }
}

// ---- Phase B: 128-step recurrence. 4 independent batch-groups x 64 blocks.
// Group g owns batch rows 16g..16g+15; block owns 64 N-cols (Wh slab 132 KB in
// LDS). Per-wave arrival + per-group flat barrier (fire-and-forget IF$ atomics),
// ZERO __syncthreads in the loop. x-GEMM for step t+1 executes inside the
// barrier-wait window (independent of h). Ring-buffered h (fresh lines -> plain
// cached loads never stale); h written via agent-scope write-through stores. ----
__global__ void __launch_bounds__(256, 1) phaseB_k(const unsigned short* __restrict__ xbf,
                                                   const unsigned short* __restrict__ WXT,
                                                   const unsigned short* __restrict__ WHT,
                                                   const float* __restrict__ biasI,
                                                   unsigned short* __restrict__ hring,
                                                   int* __restrict__ rootc) {
  __shared__ unsigned short Wh[64][1032];     // 64 n-cols x 1024 k (+8 pad): 132 KB
  __shared__ float Pl[4][16][16];             // per-wave transpose staging
  int tid = threadIdx.x;
  int grp = blockIdx.x >> 6;                  // 0..3 : batch group
  int blk = blockIdx.x & 63;                  // 0..63: N-col block within group
  int n0  = blk * 64;
  for (int c = tid; c < 64 * 128; c += 256) {
    int row = c >> 7, ch = c & 127;
    *(uint4*)&Wh[row][ch * 8] = *(const uint4*)&WHT[(size_t)(n0 + row) * HDIM + ch * 8];
  }
  __syncthreads();
  int w = tid >> 6, lane = tid & 63;
  int col = lane & 15, quad = lane >> 4;
  int gbatch = grp * 16 + col;                // A-frag batch row AND elementwise batch
  const unsigned short* whp = &Wh[w * 16 + col][quad * 8];
  const unsigned short* wxp = WXT + (size_t)(n0 + w * 16 + col) * FDIM + quad * 8;
  float4 bv = *(const float4*)&biasI[n0 + w * 16 + quad * 4];  // lane's unit gate biases
  int jbase = blk * 16 + w * 4;               // unit base for h store
  float creg = 0.0f;                          // c state thread-private
  // prologue: gx for t=0 (h_0 = 0, so gates = gx + bias at t=0 plus zero h-GEMM)
  fv4 gx0 = {0.f, 0.f, 0.f, 0.f}, gx1 = {0.f, 0.f, 0.f, 0.f};
  {
    const unsigned short* xrow = xbf + (size_t)gbatch * FDIM + quad * 8;
#pragma unroll
    for (int k0 = 0; k0 < FDIM; k0 += 64) {
      bfv8 a0 = *(const bfv8*)(xrow + k0);
      bfv8 b0 = *(const bfv8*)(wxp + k0);
      bfv8 a1 = *(const bfv8*)(xrow + k0 + 32);
      bfv8 b1 = *(const bfv8*)(wxp + k0 + 32);
      gx0 = __builtin_amdgcn_mfma_f32_16x16x32_bf16(a0, b0, gx0, 0, 0, 0);
      gx1 = __builtin_amdgcn_mfma_f32_16x16x32_bf16(a1, b1, gx1, 0, 0, 0);
    }
  }
  for (int t = 0; t < T_STEPS; ++t) {
    const unsigned short* hin  = hring + (size_t)t * HSLOT;
    unsigned short*       hout = hring + (size_t)(t + 1) * HSLOT;
    // h A-fragments (16 group-batch rows x K=1024), plain cached 16B loads.
    const uint4* hq = (const uint4*)(hin + (size_t)gbatch * HDIM + quad * 8);
    uint4 hs[32];
#pragma unroll
    for (int f = 0; f < 32; ++f) hs[f] = hq[f * 4];
    fv4 acc0 = gx0, acc1 = gx1;               // start from prefetched x-GEMM result
#pragma unroll
    for (int f = 0; f < 32; f += 2) {
      union { uint4 q; bfv8 v; } ua, ub;
      ua.q = hs[f];
      ub.q = hs[f + 1];
      bfv8 b0 = *(const bfv8*)(whp + f * 32);
      bfv8 b1 = *(const bfv8*)(whp + (f + 1) * 32);
      acc0 = __builtin_amdgcn_mfma_f32_16x16x32_bf16(ua.v, b0, acc0, 0, 0, 0);
      acc1 = __builtin_amdgcn_mfma_f32_16x16x32_bf16(ub.v, b1, acc1, 0, 0, 0);
    }
    fv4 acc = acc0 + acc1;
    // Wave-local transpose through LDS (writer wave == reader wave; no barrier).
#pragma unroll
    for (int r = 0; r < 4; ++r) Pl[w][quad * 4 + r][col] = acc[r];  // D: m=quad*4+r, n=col
    asm volatile("" ::: "memory");
    __builtin_amdgcn_s_waitcnt(0);            // ds_writes visible to own wave's ds_read
    asm volatile("" ::: "memory");
    float4 pv = *(const float4*)&Pl[w][col][quad * 4];  // (batch=col, 4 gates of unit quad)
    float fg = sigm(pv.x + bv.x);
    float ig = sigm(pv.y + bv.y);
    float og = sigm(pv.z + bv.z);
    float av = pv.w + bv.w;
    float cn = ig * tanh_f(av) + fg * creg;
    float hn = og * tanh_f(cn);
    creg = cn;
    // Pack 4 units (quad 0..3) of batch `col` via shuffles -> one 8B store.
    unsigned int u = f2b(hn);
    unsigned int a0 = __shfl((int)u, col, 64);
    unsigned int a1 = __shfl((int)u, col + 16, 64);
    unsigned int a2 = __shfl((int)u, col + 32, 64);
    unsigned int a3 = __shfl((int)u, col + 48, 64);
    if (quad == 0) {
      u64 pk = (u64)(a0 & 0xFFFFu) | ((u64)(a1 & 0xFFFFu) << 16)
             | ((u64)(a2 & 0xFFFFu) << 32) | ((u64)(a3 & 0xFFFFu) << 48);
      __hip_atomic_store((u64*)(hout + (size_t)(grp * 16 + col) * HDIM + jbase), pk,
                         __ATOMIC_RELAXED, __HIP_MEMORY_SCOPE_AGENT);
    }
    asm volatile("" ::: "memory");
    __builtin_amdgcn_s_waitcnt(0);            // drain write-through stores to IF$
    // Per-wave arrival: fire-and-forget agent atomic (no dependent round-trip).
    int* rootp = rootc + (t * 4 + grp) * 16;
    if (lane == 0)
      __hip_atomic_fetch_add(rootp, 1, __ATOMIC_RELAXED, __HIP_MEMORY_SCOPE_AGENT);
    asm volatile("" ::: "memory");
    // x-GEMM for t+1 executes inside the barrier-wait window (independent of h).
    if (t + 1 < T_STEPS) {
      fv4 g0 = {0.f, 0.f, 0.f, 0.f}, g1 = {0.f, 0.f, 0.f, 0.f};
      const unsigned short* xrow = xbf + (size_t)((t + 1) * BATCH + gbatch) * FDIM + quad * 8;
#pragma unroll
      for (int k0 = 0; k0 < FDIM; k0 += 64) {
        bfv8 a0v = *(const bfv8*)(xrow + k0);
        bfv8 b0v = *(const bfv8*)(wxp + k0);
        bfv8 a1v = *(const bfv8*)(xrow + k0 + 32);
        bfv8 b1v = *(const bfv8*)(wxp + k0 + 32);
        g0 = __builtin_amdgcn_mfma_f32_16x16x32_bf16(a0v, b0v, g0, 0, 0, 0);
        g1 = __builtin_amdgcn_mfma_f32_16x16x32_bf16(a1v, b1v, g1, 0, 0, 0);
      }
      gx0 = g0; gx1 = g1;
    }
    asm volatile("" ::: "memory");
    // Poll group barrier: 64 blocks x 4 waves = 256 arrivals.
    if (lane == 0) {
      while (__hip_atomic_load(rootp, __ATOMIC_RELAXED, __HIP_MEMORY_SCOPE_AGENT) < 256)
        __builtin_amdgcn_s_sleep(1);
    }
    asm volatile("" ::: "memory");
  }
}

// ---- Phase C: out = h @ fco_W + fco_b ----
__global__ void phaseC_k(const unsigned short* __restrict__ h,
                         const void* __restrict__ fw, const void* __restrict__ fb,
                         const int* __restrict__ flagp, void* __restrict__ out) {
  int idx = blockIdx.x * 256 + threadIdx.x;
  if (idx >= BATCH * NCLS) return;
  int b = idx / NCLS, cc = idx - b * NCLS;
  const unsigned short* hr = h + b * HDIM;
  float acc = 0.f;
  if (*flagp) {
    const unsigned short* fwp = (const unsigned short*)fw;
    for (int k = 0; k < HDIM; ++k)
      acc = fmaf(b2f(hr[k]), b2f(fwp[k * NCLS + cc]), acc);
    acc += b2f(((const unsigned short*)fb)[cc]);
    ((unsigned short*)out)[idx] = f2b(acc);
  } else {
    const float* fwp = (const float*)fw;
    for (int k = 0; k < HDIM; ++k)
      acc = fmaf(b2f(hr[k]), fwp[k * NCLS + cc], acc);
    acc += ((const float*)fb)[cc];
    ((float*)out)[idx] = acc;
  }
}

extern "C" void kernel_launch(void* const* d_in, const int* in_sizes, int n_in,
                              void* d_out, int out_size, void* d_ws, size_t ws_size,
                              hipStream_t stream) {
  const void* x   = d_in[0];
  const void* wfx = d_in[1];  const void* bfv = d_in[2];  const void* wfh = d_in[3];
  const void* wix = d_in[4];  const void* biv = d_in[5];  const void* wih = d_in[6];
  const void* wox = d_in[7];  const void* bov = d_in[8];  const void* woh = d_in[9];
  const void* wcx = d_in[10]; const void* bcv = d_in[11]; const void* wch = d_in[12];
  const void* fcw = d_in[13]; const void* fcb = d_in[14];

  char* ws = (char*)d_ws;
  int*            flag  = (int*)           (ws);                 // 256 B
  unsigned short* WXT   = (unsigned short*)(ws + 256);           // 4 MB
  unsigned short* WHT   = (unsigned short*)(ws + 4194560);       // 8 MB
  float*          biasI = (float*)         (ws + 12583168);      // 16 KB
  unsigned short* xbf   = (unsigned short*)(ws + 12599552);      // 8 MB
  unsigned short* hring = (unsigned short*)(ws + 20988160);      // 129 x 128 KB = 16.9 MB
  int*            rootc = (int*)           (ws + 37896448);      // 32 KB -> total ~37.9 MB

  detect_k<<<1, 256, 0, stream>>>((const unsigned short*)x, flag);
  prep_k<<<PREP_TOTAL / 256, 256, 0, stream>>>(x, wfx, wix, wox, wcx,
                                               wfh, wih, woh, wch,
                                               bfv, biv, bov, bcv,
                                               flag, xbf, WXT, WHT, biasI);
  hipMemsetAsync(hring, 0, 131072, stream);                      // h[0] = 0
  hipMemsetAsync(rootc, 0, 32768, stream);                       // barrier counters

  const unsigned short* p_x = xbf;
  const unsigned short* p_wx = WXT;
  const unsigned short* p_wh = WHT;
  const float* p_bi = biasI;
  unsigned short* p_hr = hring;
  int* p_cn = rootc;
  void* kargs[] = { (void*)&p_x, (void*)&p_wx, (void*)&p_wh, (void*)&p_bi,
                    (void*)&p_hr, (void*)&p_cn };
  hipLaunchCooperativeKernel((void*)phaseB_k, dim3(256), dim3(256), kargs, 0, stream);

  // final h is ring slot 128
  phaseC_k<<<(BATCH * NCLS + 255) / 256, 256, 0, stream>>>(hring + 128 * HSLOT, fcw, fcb,
                                                           flag, d_out);
}

// Round 10
// 1316.659 us; speedup vs baseline: 2.2913x; 1.0628x over previous
//
#include <hip/hip_runtime.h>
#include <hip/hip_cooperative_groups.h>

typedef short bfv8 __attribute__((ext_vector_type(8)));  // 8 x bf16 (4 VGPRs)
typedef float fv4  __attribute__((ext_vector_type(4)));  // 4 x f32 accum
typedef unsigned long long u64;

#define T_STEPS 128
#define BATCH   64
#define FDIM    512
#define HDIM    1024
#define NCOL    4096   // 4*HDIM, gate-interleaved: n = j*4 + g (g: 0=f,1=i,2=o,3=c)
#define NCLS    513
#define HSLOT   65536  // elements per h ring slot (64 x 1024)

#define PREP_N0 4194304            // convert_x  (T*B*F)
#define PREP_N1 2097152            // expand_x   (NCOL*FDIM)
#define PREP_N2 4194304            // expand_h   (NCOL*HDIM)
#define PREP_N3 4096               // bias
#define PREP_TOTAL (PREP_N0 + PREP_N1 + PREP_N2 + PREP_N3)

static __device__ __forceinline__ float b2f(unsigned short u) {
  union { unsigned int i; float f; } v; v.i = ((unsigned int)u) << 16; return v.f;
}
static __device__ __forceinline__ unsigned short f2b(float f) {
  union { float f; unsigned int i; } v; v.f = f;
  unsigned int r = v.i + 0x7FFFu + ((v.i >> 16) & 1u);   // RNE
  return (unsigned short)(r >> 16);
}
static __device__ __forceinline__ float sigm(float x) { return 1.0f / (1.0f + __expf(-x)); }
static __device__ __forceinline__ float tanh_f(float x) {
  float e = __expf(-2.0f * fabsf(x));
  float t = (1.0f - e) / (1.0f + e);
  return x >= 0.0f ? t : -t;
}

// ---- dtype detector: bf16 mode iff even-index ushorts look like bf16 N(0,1) ----
__global__ void detect_k(const unsigned short* __restrict__ xr, int* __restrict__ flag) {
  __shared__ int cnt;
  if (threadIdx.x == 0) cnt = 0;
  __syncthreads();
  int local = 0;
  for (int s = 0; s < 4; ++s) {
    int i = threadIdx.x + 256 * s;
    unsigned short u = xr[2 * i];
    int e = (u >> 7) & 0xFF;
    if (e >= 112 && e <= 131) local++;
  }
  atomicAdd(&cnt, local);
  __syncthreads();
  if (threadIdx.x == 0) *flag = (cnt >= 512) ? 1 : 0;
}

// ---- merged prep: convert x, expand WXT/WHT (tessarine big, transposed,
// gate-interleaved), bias. comp = rb ^ cb ; sign = - iff (rb odd) && (cb even).
__global__ void prep_k(const void* __restrict__ x,
                       const void* w0x, const void* w1x, const void* w2x, const void* w3x,
                       const void* w0h, const void* w1h, const void* w2h, const void* w3h,
                       const void* b0, const void* b1, const void* b2, const void* b3,
                       const int* __restrict__ flagp,
                       unsigned short* __restrict__ xbf,
                       unsigned short* __restrict__ WXT,
                       unsigned short* __restrict__ WHT,
                       float* __restrict__ biasI) {
  int fl = *flagp;
  long idx = (long)blockIdx.x * 256 + threadIdx.x;
  if (idx < PREP_N0) {
    int i = (int)idx;
    xbf[i] = fl ? ((const unsigned short*)x)[i] : f2b(((const float*)x)[i]);
    return;
  }
  idx -= PREP_N0;
  if (idx < PREP_N1) {
    int i = (int)idx;
    int n = i >> 9, k = i & 511;
    int j = n >> 2, g = n & 3;
    int rb = k >> 7, p = k & 127;               // FDIM/4 = 128
    int cb = j >> 8, q = j & 255;               // HDIM/4 = 256
    int comp = rb ^ cb;
    int neg = (rb & 1) && !(cb & 1);
    const void* W = (g == 0) ? w0x : (g == 1) ? w1x : (g == 2) ? w2x : w3x;
    int off = comp * (128 * 256) + p * 256 + q;
    unsigned short v;
    if (fl) { v = ((const unsigned short*)W)[off]; if (neg) v ^= 0x8000u; }
    else    { float f = ((const float*)W)[off]; if (neg) f = -f; v = f2b(f); }
    WXT[i] = v;
    return;
  }
  idx -= PREP_N1;
  if (idx < PREP_N2) {
    int i = (int)idx;
    int n = i >> 10, k = i & 1023;
    int j = n >> 2, g = n & 3;
    int rb = k >> 8, p = k & 255;               // HDIM/4 = 256
    int cb = j >> 8, q = j & 255;
    int comp = rb ^ cb;
    int neg = (rb & 1) && !(cb & 1);
    const void* W = (g == 0) ? w0h : (g == 1) ? w1h : (g == 2) ? w2h : w3h;
    int off = comp * (256 * 256) + p * 256 + q;
    unsigned short v;
    if (fl) { v = ((const unsigned short*)W)[off]; if (neg) v ^= 0x8000u; }
    else    { float f = ((const float*)W)[off]; if (neg) f = -f; v = f2b(f); }
    WHT[i] = v;
    return;
  }
  idx -= PREP_N2;
  {
    int i = (int)idx;                           // < 4096
    int j = i >> 2, g = i & 3;
    const void* B = (g == 0) ? b0 : (g == 1) ? b1 : (g == 2) ? b2 : b3;
    biasI[i] = fl ? b2f(((const unsigned short*)B)[j]) : ((const float*)B)[j];
  }
}

// ---- Phase B: 128-step recurrence. 4 independent batch-groups x 64 blocks.
// R10 KEY CHANGE: contention-free barrier. R6/R7 both funneled 256 same-address
// agent-scope fetch_adds per step into ONE counter (serialized RMW at IF$,
// ~4-5 us/step). Now: arrival = one plain agent store per block to its OWN
// 64B-strided flag (value t+1, monotone, single-writer); poll = each wave's 64
// lanes gather all 64 group flags in ONE L2-bypassing atomic-load instruction
// + __ballot. Zero same-address traffic. Rest identical to passing R7. ----
__global__ void __launch_bounds__(256, 1) phaseB_k(const unsigned short* __restrict__ xbf,
                                                   const unsigned short* __restrict__ WXT,
                                                   const unsigned short* __restrict__ WHT,
                                                   const float* __restrict__ biasI,
                                                   unsigned short* __restrict__ hring,
                                                   int* __restrict__ flags) {
  __shared__ unsigned short Wh[64][1032];     // 64 n-cols x 1024 k (+8 pad): 132 KB
  __shared__ float Pl[4][16][16];             // per-wave transpose staging
  int tid = threadIdx.x;
  int grp = blockIdx.x >> 6;                  // 0..3 : batch group
  int blk = blockIdx.x & 63;                  // 0..63: N-col block within group
  int n0  = blk * 64;
  for (int c = tid; c < 64 * 128; c += 256) {
    int row = c >> 7, ch = c & 127;
    *(uint4*)&Wh[row][ch * 8] = *(const uint4*)&WHT[(size_t)(n0 + row) * HDIM + ch * 8];
  }
  __syncthreads();
  int w = tid >> 6, lane = tid & 63;
  int col = lane & 15, quad = lane >> 4;
  int gbatch = grp * 16 + col;                // A-frag batch row AND elementwise batch
  const unsigned short* whp = &Wh[w * 16 + col][quad * 8];
  const unsigned short* wxp = WXT + (size_t)(n0 + w * 16 + col) * FDIM + quad * 8;
  float4 bv = *(const float4*)&biasI[n0 + w * 16 + quad * 4];  // lane's unit gate biases
  int jbase = blk * 16 + w * 4;               // unit base for h store
  int* myflag   = flags + (grp * 64 + blk) * 16;   // this block's flag (64 B stride)
  int* pollflag = flags + (grp * 64 + lane) * 16;  // lane-parallel poll target
  float creg = 0.0f;                          // c state thread-private
  // prologue: gx for t=0
  fv4 gx0 = {0.f, 0.f, 0.f, 0.f}, gx1 = {0.f, 0.f, 0.f, 0.f};
  {
    const unsigned short* xrow = xbf + (size_t)gbatch * FDIM + quad * 8;
#pragma unroll
    for (int k0 = 0; k0 < FDIM; k0 += 64) {
      bfv8 a0 = *(const bfv8*)(xrow + k0);
      bfv8 b0 = *(const bfv8*)(wxp + k0);
      bfv8 a1 = *(const bfv8*)(xrow + k0 + 32);
      bfv8 b1 = *(const bfv8*)(wxp + k0 + 32);
      gx0 = __builtin_amdgcn_mfma_f32_16x16x32_bf16(a0, b0, gx0, 0, 0, 0);
      gx1 = __builtin_amdgcn_mfma_f32_16x16x32_bf16(a1, b1, gx1, 0, 0, 0);
    }
  }
  for (int t = 0; t < T_STEPS; ++t) {
    const unsigned short* hin  = hring + (size_t)t * HSLOT;
    unsigned short*       hout = hring + (size_t)(t + 1) * HSLOT;
    // h A-fragments (16 group-batch rows x K=1024), plain cached 16B loads
    // (ring slot lines are fresh -> can never be stale).
    const uint4* hq = (const uint4*)(hin + (size_t)gbatch * HDIM + quad * 8);
    uint4 hs[32];
#pragma unroll
    for (int f = 0; f < 32; ++f) hs[f] = hq[f * 4];
    fv4 acc0 = gx0, acc1 = gx1;               // start from prefetched x-GEMM result
#pragma unroll
    for (int f = 0; f < 32; f += 2) {
      union { uint4 q; bfv8 v; } ua, ub;
      ua.q = hs[f];
      ub.q = hs[f + 1];
      bfv8 b0 = *(const bfv8*)(whp + f * 32);
      bfv8 b1 = *(const bfv8*)(whp + (f + 1) * 32);
      acc0 = __builtin_amdgcn_mfma_f32_16x16x32_bf16(ua.v, b0, acc0, 0, 0, 0);
      acc1 = __builtin_amdgcn_mfma_f32_16x16x32_bf16(ub.v, b1, acc1, 0, 0, 0);
    }
    fv4 acc = acc0 + acc1;
    // Wave-local transpose through LDS (writer wave == reader wave; no barrier).
#pragma unroll
    for (int r = 0; r < 4; ++r) Pl[w][quad * 4 + r][col] = acc[r];  // D: m=quad*4+r, n=col
    asm volatile("" ::: "memory");
    __builtin_amdgcn_s_waitcnt(0);            // ds_writes visible to own wave's ds_read
    asm volatile("" ::: "memory");
    float4 pv = *(const float4*)&Pl[w][col][quad * 4];  // (batch=col, 4 gates of unit quad)
    float fg = sigm(pv.x + bv.x);
    float ig = sigm(pv.y + bv.y);
    float og = sigm(pv.z + bv.z);
    float av = pv.w + bv.w;
    float cn = ig * tanh_f(av) + fg * creg;
    float hn = og * tanh_f(cn);
    creg = cn;
    // Pack 4 units (quad 0..3) of batch `col` via shuffles -> one 8B store.
    unsigned int u = f2b(hn);
    unsigned int a0 = __shfl((int)u, col, 64);
    unsigned int a1 = __shfl((int)u, col + 16, 64);
    unsigned int a2 = __shfl((int)u, col + 32, 64);
    unsigned int a3 = __shfl((int)u, col + 48, 64);
    if (quad == 0) {
      u64 pk = (u64)(a0 & 0xFFFFu) | ((u64)(a1 & 0xFFFFu) << 16)
             | ((u64)(a2 & 0xFFFFu) << 32) | ((u64)(a3 & 0xFFFFu) << 48);
      __hip_atomic_store((u64*)(hout + (size_t)(grp * 16 + col) * HDIM + jbase), pk,
                         __ATOMIC_RELAXED, __HIP_MEMORY_SCOPE_AGENT);
    }
    asm volatile("" ::: "memory");
    __builtin_amdgcn_s_waitcnt(0);            // this wave's h stores acked at IF$
    __syncthreads();                          // => all 4 waves' h stores acked
    // Arrival: single-writer plain agent store (no RMW, own cacheline).
    if (tid == 0)
      __hip_atomic_store(myflag, t + 1, __ATOMIC_RELAXED, __HIP_MEMORY_SCOPE_AGENT);
    asm volatile("" ::: "memory");
    // x-GEMM for t+1 executes inside the barrier-wait window (independent of h).
    if (t + 1 < T_STEPS) {
      fv4 g0 = {0.f, 0.f, 0.f, 0.f}, g1 = {0.f, 0.f, 0.f, 0.f};
      const unsigned short* xrow = xbf + (size_t)((t + 1) * BATCH + gbatch) * FDIM + quad * 8;
#pragma unroll
      for (int k0 = 0; k0 < FDIM; k0 += 64) {
        bfv8 a0v = *(const bfv8*)(xrow + k0);
        bfv8 b0v = *(const bfv8*)(wxp + k0);
        bfv8 a1v = *(const bfv8*)(xrow + k0 + 32);
        bfv8 b1v = *(const bfv8*)(wxp + k0 + 32);
        g0 = __builtin_amdgcn_mfma_f32_16x16x32_bf16(a0v, b0v, g0, 0, 0, 0);
        g1 = __builtin_amdgcn_mfma_f32_16x16x32_bf16(a1v, b1v, g1, 0, 0, 0);
      }
      gx0 = g0; gx1 = g1;
    }
    asm volatile("" ::: "memory");
    // Poll: 64 lanes gather all 64 group flags in one instruction (IF$ reads).
    for (;;) {
      int v = __hip_atomic_load(pollflag, __ATOMIC_RELAXED, __HIP_MEMORY_SCOPE_AGENT);
      if (__ballot(v >= t + 1) == ~0ull) break;
      __builtin_amdgcn_s_sleep(1);
    }
    asm volatile("" ::: "memory");
  }
}

// ---- Phase C: out = h @ fco_W + fco_b ----
__global__ void phaseC_k(const unsigned short* __restrict__ h,
                         const void* __restrict__ fw, const void* __restrict__ fb,
                         const int* __restrict__ flagp, void* __restrict__ out) {
  int idx = blockIdx.x * 256 + threadIdx.x;
  if (idx >= BATCH * NCLS) return;
  int b = idx / NCLS, cc = idx - b * NCLS;
  const unsigned short* hr = h + b * HDIM;
  float acc = 0.f;
  if (*flagp) {
    const unsigned short* fwp = (const unsigned short*)fw;
    for (int k = 0; k < HDIM; ++k)
      acc = fmaf(b2f(hr[k]), b2f(fwp[k * NCLS + cc]), acc);
    acc += b2f(((const unsigned short*)fb)[cc]);
    ((unsigned short*)out)[idx] = f2b(acc);
  } else {
    const float* fwp = (const float*)fw;
    for (int k = 0; k < HDIM; ++k)
      acc = fmaf(b2f(hr[k]), fwp[k * NCLS + cc], acc);
    acc += ((const float*)fb)[cc];
    ((float*)out)[idx] = acc;
  }
}

extern "C" void kernel_launch(void* const* d_in, const int* in_sizes, int n_in,
                              void* d_out, int out_size, void* d_ws, size_t ws_size,
                              hipStream_t stream) {
  const void* x   = d_in[0];
  const void* wfx = d_in[1];  const void* bfv = d_in[2];  const void* wfh = d_in[3];
  const void* wix = d_in[4];  const void* biv = d_in[5];  const void* wih = d_in[6];
  const void* wox = d_in[7];  const void* bov = d_in[8];  const void* woh = d_in[9];
  const void* wcx = d_in[10]; const void* bcv = d_in[11]; const void* wch = d_in[12];
  const void* fcw = d_in[13]; const void* fcb = d_in[14];

  char* ws = (char*)d_ws;
  int*            flag  = (int*)           (ws);                 // 256 B
  unsigned short* WXT   = (unsigned short*)(ws + 256);           // 4 MB
  unsigned short* WHT   = (unsigned short*)(ws + 4194560);       // 8 MB
  float*          biasI = (float*)         (ws + 12583168);      // 16 KB
  unsigned short* xbf   = (unsigned short*)(ws + 12599552);      // 8 MB
  unsigned short* hring = (unsigned short*)(ws + 20988160);      // 129 x 128 KB = 16.9 MB
  int*            flags = (int*)           (ws + 37896448);      // 16 KB -> total ~37.9 MB

  detect_k<<<1, 256, 0, stream>>>((const unsigned short*)x, flag);
  prep_k<<<PREP_TOTAL / 256, 256, 0, stream>>>(x, wfx, wix, wox, wcx,
                                               wfh, wih, woh, wch,
                                               bfv, biv, bov, bcv,
                                               flag, xbf, WXT, WHT, biasI);
  hipMemsetAsync(hring, 0, 131072, stream);                      // h[0] = 0
  hipMemsetAsync(flags, 0, 16384, stream);                       // barrier flags

  const unsigned short* p_x = xbf;
  const unsigned short* p_wx = WXT;
  const unsigned short* p_wh = WHT;
  const float* p_bi = biasI;
  unsigned short* p_hr = hring;
  int* p_fl = flags;
  void* kargs[] = { (void*)&p_x, (void*)&p_wx, (void*)&p_wh, (void*)&p_bi,
                    (void*)&p_hr, (void*)&p_fl };
  hipLaunchCooperativeKernel((void*)phaseB_k, dim3(256), dim3(256), kargs, 0, stream);

  // final h is ring slot 128
  phaseC_k<<<(BATCH * NCLS + 255) / 256, 256, 0, stream>>>(hring + 128 * HSLOT, fcw, fcb,
                                                           flag, d_out);
}